// Round 11
// baseline (398.663 us; speedup 1.0000x reference)
//
#include <hip/hip_runtime.h>
#include <hip/hip_bf16.h>

#define Bt 16
#define Ct 16
#define Nt 64
#define KITERt 4

// ---------- fp32 weight block offsets (floats) ----------
// wq@0(512) bq@512(32) wk@544(512) bk@1056(32) wm@1088(2304) bm@3392(16)
// w1@3408(4096) b1@7504(64) w2@7568(4096) b2@11664(64) wo@11728(64) bo@11792(1)
// gb@11793(16) wg@11809(9216) bg@21025(32) wc@21057(4608) bc@25665(16)
#define WF_TOTAL 25681
// swizzled bf16 MFMA B-frags (16x16x32): WgS 9216 | WcS 4608 | WmS 2560
#define SWZ_TOTAL 16384
#define SETUP_IDX (WF_TOTAL + 4096 + Nt + SWZ_TOTAL)
#define SAH_STRIDE 40   // shorts/padded pixel: 80B = 20 banks -> 2-way (free)
#define SNB_STRIDE 20   // shorts/padded pixel: 40B = 10 banks -> ~2-way (free)

typedef __attribute__((ext_vector_type(8))) short bf16x8;
typedef __attribute__((ext_vector_type(4))) short s16x4;
typedef __attribute__((ext_vector_type(4))) float f32x4;

__device__ inline short f2bs(float f) {
    __hip_bfloat16 h = __float2bfloat16(f);
    short s; __builtin_memcpy(&s, &h, 2); return s;
}
__device__ inline float bs2f(short s) {
    __hip_bfloat16 h; __builtin_memcpy(&h, &s, 2);
    return __bfloat162float(h);
}
__device__ inline float loadf(const void* p, int i, int isf32) {
    return isf32 ? ((const float*)p)[i]
                 : __bfloat162float(((const __hip_bfloat16*)p)[i]);
}
__device__ inline float sigm(float x) {
    return __builtin_amdgcn_rcpf(1.f + __expf(-x));
}
__device__ inline float tanh_fast(float x) {
    float e = __expf(2.f * x);              // inf-safe: rcp(inf)=0 -> 1; e=0 -> -1
    return 1.f - 2.f * __builtin_amdgcn_rcpf(e + 1.f);
}

// ---------------- setup: flag, weights->fp32, Tswz, nbr table (parallel),
// swizzled weights, unpack seed -> Xb bf16 [b][n][pix][ch], initial q/k --------
__global__ __launch_bounds__(256) void setup_kernel(
    const void* __restrict__ seed,
    const void* __restrict__ wq, const void* __restrict__ bq,
    const void* __restrict__ wk, const void* __restrict__ bk,
    const void* __restrict__ wm, const void* __restrict__ bm,
    const void* __restrict__ w1, const void* __restrict__ b1,
    const void* __restrict__ w2, const void* __restrict__ b2,
    const void* __restrict__ wo, const void* __restrict__ bo,
    const void* __restrict__ gw, const void* __restrict__ gb,
    const void* __restrict__ wg, const void* __restrict__ bg,
    const void* __restrict__ wc, const void* __restrict__ bc,
    const int* __restrict__ edge, int E,
    float* __restrict__ Wf, float* __restrict__ Tswz,
    int* __restrict__ counts, int* __restrict__ nbrs,
    __hip_bfloat16* __restrict__ swz,
    short* __restrict__ Xb, float* __restrict__ qv0, float* __restrict__ kv0,
    int* __restrict__ flag)
{
    __shared__ float sred[4];
    __shared__ int sflag;
    __shared__ float xred[64];
    __shared__ int snb[256];
    int bn = blockIdx.x, t = threadIdx.x;
    int lane = t & 63, wv = t >> 6;

    // ---- dtype probe: 1 sample/thread, block-reduce max of |bf16-view| ----
    {
        float v = fabsf(__bfloat162float(((const __hip_bfloat16*)seed)[t]));
        if (!(v <= 1e30f)) v = 1e30f;
#pragma unroll
        for (int off = 1; off < 64; off <<= 1) v = fmaxf(v, __shfl_xor(v, off, 64));
        if (lane == 0) sred[wv] = v;
        __syncthreads();
        if (t == 0) {
            float m = fmaxf(fmaxf(sred[0], sred[1]), fmaxf(sred[2], sred[3]));
            sflag = (m > 1e10f) ? 1 : 0;   // 1 => inputs are float32
            if (bn == 0) *flag = sflag;
        }
        __syncthreads();
    }
    int isf32 = sflag;

    // ---- block 0: parallel nbr table via direction slots (matches ref order) ----
    if (bn == 0) {
        snb[t] = 0;
        __syncthreads();
        for (int e = t; e < E; e += 256) {
            int ei = edge[2 * e], ej = edge[2 * e + 1];
            int d = ej - ei;
            int slot = (d == 1) ? 0 : (d == 8) ? 1 : (d == -1) ? 2 : 3;
            snb[ei * 4 + slot] = ej + 1;   // 0 = absent; slot order == ref edge order
        }
        __syncthreads();
        if (t < 64) {
            int dcount = 0;
            int outv[4] = {0, 0, 0, 0};
#pragma unroll
            for (int s = 0; s < 4; ++s) {
                int v = snb[t * 4 + s];
                if (v) outv[dcount++] = v - 1;
            }
            counts[t] = dcount;
#pragma unroll
            for (int s = 0; s < 4; ++s) nbrs[t * 4 + s] = outv[s];
        }
    }

    // ---- part 1: indexed weight / table prep ----
    int idx = bn * 256 + t;
    if (idx < WF_TOTAL) {
        int i = idx;
        const void* base;
        if (i < 512) base = wq;
        else if ((i -= 512) < 32) base = bq;
        else if ((i -= 32) < 512) base = wk;
        else if ((i -= 512) < 32) base = bk;
        else if ((i -= 32) < 2304) base = wm;
        else if ((i -= 2304) < 16) base = bm;
        else if ((i -= 16) < 4096) base = w1;
        else if ((i -= 4096) < 64) base = b1;
        else if ((i -= 64) < 4096) base = w2;
        else if ((i -= 4096) < 64) base = b2;
        else if ((i -= 64) < 64) base = wo;
        else if ((i -= 64) < 1) base = bo;
        else if ((i -= 1) < 16) base = gb;
        else if ((i -= 16) < 9216) base = wg;
        else if ((i -= 9216) < 32) base = bg;
        else if ((i -= 32) < 4608) base = wc;
        else { i -= 4608; base = bc; }
        Wf[idx] = loadf(base, i, isf32);
    } else if (idx < WF_TOTAL + 4096) {
        // T in MFMA C-layout order: Tswz[t*16 + mt*4+r] = T[ch=n16][pix(wv,mt,quad,r)]
        int j = idx - WF_TOTAL;
        int tt = j >> 4, rr = j & 15;
        int wv2 = tt >> 6, ln = tt & 63, qd = ln >> 4, nn = ln & 15;
        int mt = rr >> 2, r2 = rr & 3;
        int pix = (wv2 * 4 + mt) * 16 + qd * 4 + r2;
        int y = pix >> 4, x = pix & 15;
        float s = 0.f;
        for (int ky = 0; ky < 3; ++ky)
            for (int kx = 0; kx < 3; ++kx) {
                int yy = y + ky - 1, xx = x + kx - 1;
                if (yy >= 0 && yy < 16 && xx >= 0 && xx < 16)
                    s += loadf(gw, nn * 9 + ky * 3 + kx, isf32);
            }
        Tswz[j] = s;
    } else if (idx < SETUP_IDX && idx >= WF_TOTAL + 4096 + Nt) {
        // B-frag swizzle (16x16x32): elem j of lane = B[k=(lane>>4)*8+j][n=lane&15]
        int j = idx - (WF_TOTAL + 4096 + Nt);
        float val;
        if (j < 9216) {                       // WgS: 9 shifts x 2 ntiles
            int sn = j >> 9, rem = j & 511;
            int ln = rem >> 3, jj = rem & 7;
            int s = sn >> 1, nt = sn & 1;
            int ci = (ln >> 4) * 8 + jj;
            int co = nt * 16 + (ln & 15);
            val = loadf(wg, co * 288 + ci * 9 + s, isf32);
        } else if (j < 9216 + 4608) {         // WcS: 9 shifts
            int j1 = j - 9216;
            int s = j1 >> 9, rem = j1 & 511;
            int ln = rem >> 3, jj = rem & 7;
            int ci = (ln >> 4) * 8 + jj;
            int co = ln & 15;
            val = loadf(wc, co * 288 + ci * 9 + s, isf32);
        } else {                              // WmS: 5 shift-pairs (K=32 = 2 shifts x 16 ci)
            int j2 = j - 13824;
            int sp = j2 >> 9, rem = j2 & 511;
            int ln = rem >> 3, jj = rem & 7;
            int k = (ln >> 4) * 8 + jj;
            int s = sp * 2 + (k >> 4);
            int ci = k & 15;
            int co = ln & 15;
            val = (s <= 8) ? loadf(wm, co * 144 + ci * 9 + s, isf32) : 0.f;
        }
        swz[j] = __float2bfloat16(val);
    }

    // ---- part 2: unpack own patch bn + initial q/k (raw inputs only) ----
    {
        int b = bn >> 6, n = bn & 63;
        int pq = n >> 3, qq = n & 7;
        int y = t >> 4, x = t & 15;
        float v[16];
#pragma unroll
        for (int c = 0; c < 16; ++c)
            v[c] = loadf(seed, ((b * 16 + c) * 128 + pq * 16 + y) * 128 + qq * 16 + x, isf32);
        bf16x8 o0, o1;
#pragma unroll
        for (int c = 0; c < 8; ++c) { o0[c] = f2bs(v[c]); o1[c] = f2bs(v[8 + c]); }
        short* xo = Xb + bn * 4096;
        *(bf16x8*)(xo + t * 16) = o0;
        *(bf16x8*)(xo + t * 16 + 8) = o1;
#pragma unroll
        for (int c = 0; c < 16; ++c) {
            float s = v[c];
#pragma unroll
            for (int off = 1; off < 64; off <<= 1) s += __shfl_xor(s, off, 64);
            if (lane == c) xred[wv * 16 + c] = s;
        }
        __syncthreads();
        if (t < 64) {
            int d = t & 31;
            float a = (t < 32) ? loadf(bq, d, isf32) : loadf(bk, d, isf32);
#pragma unroll
            for (int c = 0; c < 16; ++c) {
                float xm = (xred[c] + xred[16 + c] + xred[32 + c] + xred[48 + c]) * (1.f / 256.f);
                a += xm * ((t < 32) ? loadf(wq, c * 32 + d, isf32)
                                    : loadf(wk, c * 32 + d, isf32));
            }
            if (t < 32) qv0[bn * 32 + d] = a; else kv0[bn * 32 + d] = a;
        }
    }
}

// ---------------- fused iteration: one block per (b, patch) ----------------
// Double-buffered globals: reads ONLY Xin/qin/kin, writes ONLY Xout/qout/kout
// (on the last iteration writes d_out directly in NCHW layout).
// LDS: sAH [324][40] (ch0-15 = nbr-X buf0 / Magg, ch16-31 = h, kept intact);
//      sNB [324][20] (nbr-X buf1, later r*h). 8 barriers/iter at deg=4.
__global__ __launch_bounds__(256) void iter_kernel(
    const short* __restrict__ Xin, short* __restrict__ Xout,
    const float* __restrict__ qin, const float* __restrict__ kin,
    float* __restrict__ qout, float* __restrict__ kout,
    const float* __restrict__ Tswz,
    const short* __restrict__ WmS,
    const short* __restrict__ WgS,
    const short* __restrict__ WcS,
    const float* __restrict__ Wf,
    const int* __restrict__ counts, const int* __restrict__ nbrs,
    const int* __restrict__ flagp, void* __restrict__ out, int last)
{
    __shared__ __align__(16) short sAH[324 * SAH_STRIDE];
    __shared__ __align__(16) short sNB[324 * SNB_STRIDE];
    __shared__ float evs[4];
    __shared__ float xred[64];
    int bn = blockIdx.x, b = bn >> 6, i = bn & 63;
    int t = threadIdx.x, lane = t & 63, wv = t >> 6;
    int quad = lane >> 4, n16 = lane & 15;

    // ---- nbr table + neighbor-0 prefetch + MLP input prefetch ----
    int4 nb4 = *(const int4*)(nbrs + i * 4);
    int deg = counts[i];
    int ejl[4] = {nb4.x, nb4.y, nb4.z, nb4.w};
    bf16x8 nbA0, nbA1, nbB0, nbB1;
    if (deg > 0) {
        const short* mp = Xin + (b * 64 + ejl[0]) * 4096 + t * 16;
        nbA0 = *(const bf16x8*)(mp);
        nbA1 = *(const bf16x8*)(mp + 8);
    }
    float h0 = 0.f;
    if (wv < deg)
        h0 = (lane < 32) ? qin[bn * 32 + lane]
                         : kin[(b * 64 + ejl[wv]) * 32 + (lane - 32)];

    // per-lane constants
    float T_lane[16];
#pragma unroll
    for (int r = 0; r < 16; ++r) T_lane[r] = Tswz[t * 16 + r];
    float gb_l = Wf[11793 + n16];
    float bm_l = Wf[3392 + n16];

    const short* xown = Xin + bn * 4096;
    int pp = ((t >> 4) + 1) * 18 + (t & 15) + 1;   // own pixel, padded coords

    // ---- phase A: own h -> sAH ch16-31; zero borders of both regions;
    //      stage neighbor 0 into buf0 (sAH ch0-15) ----
    for (int p = t; p < 324; p += 256) {
        int yy = p / 18 - 1, xx = p % 18 - 1;
        short* row = sAH + p * SAH_STRIDE;
        if ((unsigned)yy < 16u && (unsigned)xx < 16u) {
            const short* src = xown + (yy * 16 + xx) * 16;
            *(bf16x8*)(row + 16) = *(const bf16x8*)(src);
            *(bf16x8*)(row + 24) = *(const bf16x8*)(src + 8);
        } else {
            bf16x8 z = {0, 0, 0, 0, 0, 0, 0, 0};
            *(bf16x8*)(row) = z;      *(bf16x8*)(row + 8) = z;
            *(bf16x8*)(row + 16) = z; *(bf16x8*)(row + 24) = z;
            short* row2 = sNB + p * SNB_STRIDE;
            *(bf16x8*)(row2) = z;     *(bf16x8*)(row2 + 8) = z;
        }
    }
    if (deg > 0) {
        *(bf16x8*)(sAH + pp * SAH_STRIDE) = nbA0;
        *(bf16x8*)(sAH + pp * SAH_STRIDE + 8) = nbA1;
    }

    // ---- phase B: edge MLP, one wave per incoming edge ----
    if (wv < deg) {
        const float* W1 = Wf + 3408;
        const float* W2 = Wf + 7568;
        float p0 = 0.f, p1 = 0.f, p2 = 0.f, p3 = 0.f;
#pragma unroll
        for (int j = 0; j < 64; j += 4) {
            p0 += __shfl(h0, j + 0, 64) * W1[(j + 0) * 64 + lane];
            p1 += __shfl(h0, j + 1, 64) * W1[(j + 1) * 64 + lane];
            p2 += __shfl(h0, j + 2, 64) * W1[(j + 2) * 64 + lane];
            p3 += __shfl(h0, j + 3, 64) * W1[(j + 3) * 64 + lane];
        }
        float a1 = fmaxf(Wf[7504 + lane] + ((p0 + p1) + (p2 + p3)), 0.f);
        p0 = p1 = p2 = p3 = 0.f;
#pragma unroll
        for (int j = 0; j < 64; j += 4) {
            p0 += __shfl(a1, j + 0, 64) * W2[(j + 0) * 64 + lane];
            p1 += __shfl(a1, j + 1, 64) * W2[(j + 1) * 64 + lane];
            p2 += __shfl(a1, j + 2, 64) * W2[(j + 2) * 64 + lane];
            p3 += __shfl(a1, j + 3, 64) * W2[(j + 3) * 64 + lane];
        }
        float a2 = fmaxf(Wf[11664 + lane] + ((p0 + p1) + (p2 + p3)), 0.f);
        float pe = a2 * Wf[11728 + lane];
#pragma unroll
        for (int off = 32; off; off >>= 1) pe += __shfl_down(pe, off, 64);
        if (lane == 0) evs[wv] = pe + Wf[11792];
    }
    __syncthreads();   // h + nb0 staged, borders zeroed, evs ready

    // ---- phase C: per-neighbor M conv; double-buffered staging, 1 barrier each ----
    f32x4 magg[4];
#pragma unroll
    for (int mt = 0; mt < 4; ++mt) magg[mt] = (f32x4){0.f, 0.f, 0.f, 0.f};
    for (int ii = 0; ii < deg; ++ii) {
        if (ii + 1 < deg) {                    // prefetch next neighbor into regs
            const short* mp = Xin + (b * 64 + ejl[ii + 1]) * 4096 + t * 16;
            nbB0 = *(const bf16x8*)(mp);
            nbB1 = *(const bf16x8*)(mp + 8);
        }
        // conv from buf(ii&1)
        const short* nbase = (ii & 1) ? sNB : sAH;
        int nstride = (ii & 1) ? SNB_STRIDE : SAH_STRIDE;
        float evv = evs[ii];
        f32x4 acc[4];
#pragma unroll
        for (int mt = 0; mt < 4; ++mt) acc[mt] = (f32x4){bm_l, bm_l, bm_l, bm_l};
#pragma unroll
        for (int sp = 0; sp < 5; ++sp) {
            bf16x8 Bf = *(const bf16x8*)(WmS + sp * 512 + lane * 8);
            int s2 = sp * 2 + (quad >> 1);
            if (s2 > 8) s2 = 8;                // phantom shift: B half is zero
            int ky = s2 / 3, kx = s2 - (s2 / 3) * 3;
            int cib = (quad & 1) * 8;
#pragma unroll
            for (int mt = 0; mt < 4; ++mt) {
                int pc = (wv * 4 + mt + ky) * 18 + n16 + kx;
                bf16x8 A = *(const bf16x8*)(nbase + pc * nstride + cib);
                acc[mt] = __builtin_amdgcn_mfma_f32_16x16x32_bf16(A, Bf, acc[mt], 0, 0, 0);
            }
        }
#pragma unroll
        for (int mt = 0; mt < 4; ++mt)
#pragma unroll
            for (int r = 0; r < 4; ++r)
                magg[mt][r] += sigm(evv * T_lane[mt * 4 + r] + gb_l) * acc[mt][r];
        // stage next into the OTHER buffer (its old readers finished last barrier)
        if (ii + 1 < deg) {
            short* sb = ((ii + 1) & 1) ? sNB : sAH;
            int ss = ((ii + 1) & 1) ? SNB_STRIDE : SAH_STRIDE;
            *(bf16x8*)(sb + pp * ss) = nbB0;
            *(bf16x8*)(sb + pp * ss + 8) = nbB1;
        }
        __syncthreads();   // closes: conv reads of buf(ii) AND staging of buf(ii+1)
    }
    // ---- phase D: M_agg -> buf0 (sAH ch0-15) interior (each slot exactly once) ----
#pragma unroll
    for (int mt = 0; mt < 4; ++mt)
#pragma unroll
        for (int r = 0; r < 4; ++r) {
            int p = (wv * 4 + mt + 1) * 18 + quad * 4 + r + 1;
            sAH[p * SAH_STRIDE + n16] = f2bs(magg[mt][r]);
        }
    __syncthreads();

    // ---- zr conv: 9 shifts x 2 ntiles x 4 Mtiles (A = [Magg; h] in sAH) ----
    float bz = Wf[21025 + n16], br = Wf[21025 + 16 + n16];
    f32x4 accZ[4], accR[4];
#pragma unroll
    for (int mt = 0; mt < 4; ++mt) {
        accZ[mt] = (f32x4){bz, bz, bz, bz};
        accR[mt] = (f32x4){br, br, br, br};
    }
#pragma unroll
    for (int s = 0; s < 9; ++s) {
        int ky = s / 3, kx = s - (s / 3) * 3;
        bf16x8 B0 = *(const bf16x8*)(WgS + (s * 2 + 0) * 512 + lane * 8);
        bf16x8 B1 = *(const bf16x8*)(WgS + (s * 2 + 1) * 512 + lane * 8);
#pragma unroll
        for (int mt = 0; mt < 4; ++mt) {
            int pc = (wv * 4 + mt + ky) * 18 + n16 + kx;
            bf16x8 A = *(const bf16x8*)(sAH + pc * SAH_STRIDE + quad * 8);
            accZ[mt] = __builtin_amdgcn_mfma_f32_16x16x32_bf16(A, B0, accZ[mt], 0, 0, 0);
            accR[mt] = __builtin_amdgcn_mfma_f32_16x16x32_bf16(A, B1, accR[mt], 0, 0, 0);
        }
    }
    // ---- z, r, h; r*h -> sNB (h in sAH stays intact -> no barrier pair) ----
    float zf[16], hf[16];
#pragma unroll
    for (int mt = 0; mt < 4; ++mt)
#pragma unroll
        for (int r = 0; r < 4; ++r) {
            int k = mt * 4 + r;
            int ps = (wv * 4 + mt + 1) * 18 + quad * 4 + r + 1;
            hf[k] = bs2f(sAH[ps * SAH_STRIDE + 16 + n16]);
            zf[k] = sigm(accZ[mt][r]);
            sNB[ps * SNB_STRIDE + n16] = f2bs(sigm(accR[mt][r]) * hf[k]);
        }
    __syncthreads();   // rh visible to all

    // ---- cand conv: A = [Magg (sAH ch0-15) ; r*h (sNB)] selected by quad ----
    const short* cbase = (quad < 2) ? sAH : sNB;
    int cstride = (quad < 2) ? SAH_STRIDE : SNB_STRIDE;
    int coff = (quad < 2) ? quad * 8 : (quad - 2) * 8;
    float bcl = Wf[25665 + n16];
    f32x4 accC[4];
#pragma unroll
    for (int mt = 0; mt < 4; ++mt) accC[mt] = (f32x4){bcl, bcl, bcl, bcl};
#pragma unroll
    for (int s = 0; s < 9; ++s) {
        int ky = s / 3, kx = s - (s / 3) * 3;
        bf16x8 Bc = *(const bf16x8*)(WcS + s * 512 + lane * 8);
#pragma unroll
        for (int mt = 0; mt < 4; ++mt) {
            int pc = (wv * 4 + mt + ky) * 18 + n16 + kx;
            bf16x8 A = *(const bf16x8*)(cbase + pc * cstride + coff);
            accC[mt] = __builtin_amdgcn_mfma_f32_16x16x32_bf16(A, Bc, accC[mt], 0, 0, 0);
        }
    }
    // ---- epilogue: nx = (1-z)h + z*tanh(cand) ----
    float nxv[16];
#pragma unroll
    for (int mt = 0; mt < 4; ++mt)
#pragma unroll
        for (int r = 0; r < 4; ++r) {
            int k = mt * 4 + r;
            nxv[k] = (1.f - zf[k]) * hf[k] + zf[k] * tanh_fast(accC[mt][r]);
        }

    if (!last) {
        short* xo = Xout + bn * 4096;
        float ssum = 0.f;
#pragma unroll
        for (int mt = 0; mt < 4; ++mt)
#pragma unroll
            for (int r = 0; r < 4; ++r) {
                int k = mt * 4 + r;
                ssum += nxv[k];
                int pix = (wv * 4 + mt) * 16 + quad * 4 + r;
                xo[pix * 16 + n16] = f2bs(nxv[k]);
            }
        ssum += __shfl_xor(ssum, 16, 64);
        ssum += __shfl_xor(ssum, 32, 64);
        if (lane < 16) xred[wv * 16 + lane] = ssum;
        __syncthreads();
        if (t < 64) {
            int d = t & 31;
            const float* W = (t < 32) ? Wf : Wf + 544;
            float a = (t < 32) ? Wf[512 + d] : Wf[1056 + d];
#pragma unroll
            for (int c = 0; c < 16; ++c) {
                float xc = (xred[c] + xred[16 + c] + xred[32 + c] + xred[48 + c]) * (1.f / 256.f);
                a += xc * W[c * 32 + d];
            }
            if (t < 32) qout[bn * 32 + d] = a; else kout[bn * 32 + d] = a;
        }
    } else {
        // final iteration: write d_out directly in (B,C,128,128)
        int isf32 = *flagp;
        int pq = i >> 3, qq = i & 7;
#pragma unroll
        for (int mt = 0; mt < 4; ++mt) {
            long base = ((long)(b * 16 + n16) * 128 + pq * 16 + wv * 4 + mt) * 128
                        + qq * 16 + quad * 4;
            if (isf32) {
                f32x4 v = {nxv[mt * 4], nxv[mt * 4 + 1], nxv[mt * 4 + 2], nxv[mt * 4 + 3]};
                *(f32x4*)((float*)out + base) = v;
            } else {
                s16x4 v = {f2bs(nxv[mt * 4]), f2bs(nxv[mt * 4 + 1]),
                           f2bs(nxv[mt * 4 + 2]), f2bs(nxv[mt * 4 + 3])};
                *(s16x4*)((short*)out + base) = v;
            }
        }
    }
}

extern "C" void kernel_launch(void* const* d_in, const int* in_sizes, int n_in,
                              void* d_out, int out_size, void* d_ws, size_t ws_size,
                              hipStream_t stream)
{
    const void* seed = d_in[0];
    const int* edge = (const int*)d_in[1];
    int E = in_sizes[1] / 2;  // 224

    float* ws = (float*)d_ws;
    short* Xb0 = (short*)ws;                         // 8 MB
    short* Xb1 = (short*)(ws + 2097152);             // 8 MB
    float* qv0 = ws + 4194304;                       // 32768 each
    float* kv0 = qv0 + 32768;
    float* qv1 = kv0 + 32768;
    float* kv1 = qv1 + 32768;
    float* Tswz = kv1 + 32768;                       // 4096
    float* Wf = Tswz + 4096;                         // 25681
    int* nbrs = (int*)(ws + 4355168);                // 256 ints, 16B-aligned
    int* counts = nbrs + 256;                        // 64
    int* flag = counts + 64;                         // 1
    __hip_bfloat16* swz = (__hip_bfloat16*)(ws + 4355600);  // 16384 bf16, 16B-aligned

    const short* WgS = (const short*)swz;
    const short* WcS = (const short*)(swz + 9216);
    const short* WmS = (const short*)(swz + 13824);

    setup_kernel<<<Bt * Nt, 256, 0, stream>>>(
        seed,
        d_in[2], d_in[3], d_in[4], d_in[5], d_in[6], d_in[7], d_in[8], d_in[9],
        d_in[10], d_in[11], d_in[12], d_in[13], d_in[14], d_in[15], d_in[16],
        d_in[17], d_in[18], d_in[19],
        edge, E, Wf, Tswz, counts, nbrs, swz, Xb0, qv0, kv0, flag);

    short* Xs[2] = {Xb0, Xb1};
    float* qs[2] = {qv0, qv1};
    float* ks[2] = {kv0, kv1};
    for (int it = 0; it < KITERt; ++it) {
        int in = it & 1, on = in ^ 1;
        int last = (it == KITERt - 1);
        iter_kernel<<<Bt * Nt, 256, 0, stream>>>(
            Xs[in], Xs[on], qs[in], ks[in], qs[on], ks[on],
            Tswz, WmS, WgS, WcS, Wf, counts, nbrs, flag, d_out, last);
    }
}

// Round 12
// 230.600 us; speedup vs baseline: 1.7288x; 1.7288x over previous
//
#include <hip/hip_runtime.h>
#include <hip/hip_bf16.h>

#define Bt 16
#define Ct 16
#define Nt 64
#define KITERt 4

// ---------- fp32 weight block offsets (floats) ----------
// wq@0(512) bq@512(32) wk@544(512) bk@1056(32) wm@1088(2304) bm@3392(16)
// w1@3408(4096) b1@7504(64) w2@7568(4096) b2@11664(64) wo@11728(64) bo@11792(1)
// gb@11793(16) wg@11809(9216) bg@21025(32) wc@21057(4608) bc@25665(16)
#define WF_TOTAL 25681
// swizzled bf16 MFMA B-frags: WgS 9216 | WcS 4608 | WmS 2560
#define SWZ_TOTAL 16384
#define SETUP_IDX (WF_TOTAL + 4096 + Nt + SWZ_TOTAL)
#define SAH_STRIDE 40   // shorts per padded pixel row: 80B = 20 banks -> 2-way (free)

typedef __attribute__((ext_vector_type(8))) short bf16x8;
typedef __attribute__((ext_vector_type(4))) short s16x4;
typedef __attribute__((ext_vector_type(4))) float f32x4;

__device__ inline short f2bs(float f) {
    __hip_bfloat16 h = __float2bfloat16(f);
    short s; __builtin_memcpy(&s, &h, 2); return s;
}
__device__ inline float bs2f(short s) {
    __hip_bfloat16 h; __builtin_memcpy(&h, &s, 2);
    return __bfloat162float(h);
}
__device__ inline float loadf(const void* p, int i, int isf32) {
    return isf32 ? ((const float*)p)[i]
                 : __bfloat162float(((const __hip_bfloat16*)p)[i]);
}
__device__ inline float sigm(float x) {
    return __builtin_amdgcn_rcpf(1.f + __expf(-x));
}
__device__ inline float tanh_fast(float x) {
    float e = __expf(2.f * x);              // inf-safe: rcp(inf)=0 -> 1; e=0 -> -1
    return 1.f - 2.f * __builtin_amdgcn_rcpf(e + 1.f);
}

// ---------------- setup: flag, weights->fp32, Tswz, nbr table (parallel),
// swizzled weights, unpack seed -> Xb bf16 [b][n][pix][ch], initial q/k --------
__global__ __launch_bounds__(256) void setup_kernel(
    const void* __restrict__ seed,
    const void* __restrict__ wq, const void* __restrict__ bq,
    const void* __restrict__ wk, const void* __restrict__ bk,
    const void* __restrict__ wm, const void* __restrict__ bm,
    const void* __restrict__ w1, const void* __restrict__ b1,
    const void* __restrict__ w2, const void* __restrict__ b2,
    const void* __restrict__ wo, const void* __restrict__ bo,
    const void* __restrict__ gw, const void* __restrict__ gb,
    const void* __restrict__ wg, const void* __restrict__ bg,
    const void* __restrict__ wc, const void* __restrict__ bc,
    const int* __restrict__ edge, int E,
    float* __restrict__ Wf, float* __restrict__ Tswz,
    int* __restrict__ counts, int* __restrict__ nbrs,
    __hip_bfloat16* __restrict__ swz,
    short* __restrict__ Xb, float* __restrict__ qv0, float* __restrict__ kv0,
    int* __restrict__ flag)
{
    __shared__ float sred[4];
    __shared__ int sflag;
    __shared__ float xred[64];
    __shared__ int snb[256];
    int bn = blockIdx.x, t = threadIdx.x;
    int lane = t & 63, wv = t >> 6;

    // ---- dtype probe: 1 sample/thread, block-reduce max of |bf16-view| ----
    {
        float v = fabsf(__bfloat162float(((const __hip_bfloat16*)seed)[t]));
        if (!(v <= 1e30f)) v = 1e30f;
#pragma unroll
        for (int off = 1; off < 64; off <<= 1) v = fmaxf(v, __shfl_xor(v, off, 64));
        if (lane == 0) sred[wv] = v;
        __syncthreads();
        if (t == 0) {
            float m = fmaxf(fmaxf(sred[0], sred[1]), fmaxf(sred[2], sred[3]));
            sflag = (m > 1e10f) ? 1 : 0;   // 1 => inputs are float32
            if (bn == 0) *flag = sflag;
        }
        __syncthreads();
    }
    int isf32 = sflag;

    // ---- block 0: parallel nbr table via direction slots (matches ref order) ----
    if (bn == 0) {
        snb[t] = 0;
        __syncthreads();
        for (int e = t; e < E; e += 256) {
            int ei = edge[2 * e], ej = edge[2 * e + 1];
            int d = ej - ei;
            int slot = (d == 1) ? 0 : (d == 8) ? 1 : (d == -1) ? 2 : 3;
            snb[ei * 4 + slot] = ej + 1;   // 0 = absent; slot order == ref edge order
        }
        __syncthreads();
        if (t < 64) {
            int dcount = 0;
            int outv[4] = {0, 0, 0, 0};
#pragma unroll
            for (int s = 0; s < 4; ++s) {
                int v = snb[t * 4 + s];
                if (v) outv[dcount++] = v - 1;
            }
            counts[t] = dcount;
#pragma unroll
            for (int s = 0; s < 4; ++s) nbrs[t * 4 + s] = outv[s];
        }
    }

    // ---- part 1: indexed weight / table prep ----
    int idx = bn * 256 + t;
    if (idx < WF_TOTAL) {
        int i = idx;
        const void* base;
        if (i < 512) base = wq;
        else if ((i -= 512) < 32) base = bq;
        else if ((i -= 32) < 512) base = wk;
        else if ((i -= 512) < 32) base = bk;
        else if ((i -= 32) < 2304) base = wm;
        else if ((i -= 2304) < 16) base = bm;
        else if ((i -= 16) < 4096) base = w1;
        else if ((i -= 4096) < 64) base = b1;
        else if ((i -= 64) < 4096) base = w2;
        else if ((i -= 4096) < 64) base = b2;
        else if ((i -= 64) < 64) base = wo;
        else if ((i -= 64) < 1) base = bo;
        else if ((i -= 1) < 16) base = gb;
        else if ((i -= 16) < 9216) base = wg;
        else if ((i -= 9216) < 32) base = bg;
        else if ((i -= 32) < 4608) base = wc;
        else { i -= 4608; base = bc; }
        Wf[idx] = loadf(base, i, isf32);
    } else if (idx < WF_TOTAL + 4096) {
        // T in MFMA C-layout order: Tswz[t*16 + mt*4+r] = T[ch=n16][pix(wv,mt,quad,r)]
        int j = idx - WF_TOTAL;
        int tt = j >> 4, rr = j & 15;
        int wv2 = tt >> 6, ln = tt & 63, qd = ln >> 4, nn = ln & 15;
        int mt = rr >> 2, r2 = rr & 3;
        int pix = (wv2 * 4 + mt) * 16 + qd * 4 + r2;
        int y = pix >> 4, x = pix & 15;
        float s = 0.f;
        for (int ky = 0; ky < 3; ++ky)
            for (int kx = 0; kx < 3; ++kx) {
                int yy = y + ky - 1, xx = x + kx - 1;
                if (yy >= 0 && yy < 16 && xx >= 0 && xx < 16)
                    s += loadf(gw, nn * 9 + ky * 3 + kx, isf32);
            }
        Tswz[j] = s;
    } else if (idx >= WF_TOTAL + 4096 + Nt && idx < SETUP_IDX) {
        // B-frag swizzle: element j of lane's frag holds B[k=(lane>>4)*8+j][n=lane&15]
        int j = idx - (WF_TOTAL + 4096 + Nt);
        float val;
        if (j < 9216) {                       // WgS: 9 shifts x 2 ntiles
            int sn = j >> 9, rem = j & 511;
            int ln = rem >> 3, jj = rem & 7;
            int s = sn >> 1, nt = sn & 1;
            int ci = (ln >> 4) * 8 + jj;
            int co = nt * 16 + (ln & 15);
            val = loadf(wg, co * 288 + ci * 9 + s, isf32);
        } else if (j < 9216 + 4608) {         // WcS: 9 shifts
            int j1 = j - 9216;
            int s = j1 >> 9, rem = j1 & 511;
            int ln = rem >> 3, jj = rem & 7;
            int ci = (ln >> 4) * 8 + jj;
            int co = ln & 15;
            val = loadf(wc, co * 288 + ci * 9 + s, isf32);
        } else {                              // WmS: 5 shift-pairs (K=32 = 2 shifts x 16 ci)
            int j2 = j - 13824;
            int sp = j2 >> 9, rem = j2 & 511;
            int ln = rem >> 3, jj = rem & 7;
            int k = (ln >> 4) * 8 + jj;
            int s = sp * 2 + (k >> 4);
            int ci = k & 15;
            int co = ln & 15;
            val = (s <= 8) ? loadf(wm, co * 144 + ci * 9 + s, isf32) : 0.f;
        }
        swz[j] = __float2bfloat16(val);
    }

    // ---- part 2: unpack own patch bn + initial q/k (raw inputs only) ----
    {
        int b = bn >> 6, n = bn & 63;
        int pq = n >> 3, qq = n & 7;
        int y = t >> 4, x = t & 15;
        float v[16];
#pragma unroll
        for (int c = 0; c < 16; ++c)
            v[c] = loadf(seed, ((b * 16 + c) * 128 + pq * 16 + y) * 128 + qq * 16 + x, isf32);
        bf16x8 o0, o1;
#pragma unroll
        for (int c = 0; c < 8; ++c) { o0[c] = f2bs(v[c]); o1[c] = f2bs(v[8 + c]); }
        short* xo = Xb + bn * 4096;
        *(bf16x8*)(xo + t * 16) = o0;
        *(bf16x8*)(xo + t * 16 + 8) = o1;
#pragma unroll
        for (int c = 0; c < 16; ++c) {
            float s = v[c];
#pragma unroll
            for (int off = 1; off < 64; off <<= 1) s += __shfl_xor(s, off, 64);
            if (lane == c) xred[wv * 16 + c] = s;
        }
        __syncthreads();
        if (t < 64) {
            int d = t & 31;
            float a = (t < 32) ? loadf(bq, d, isf32) : loadf(bk, d, isf32);
#pragma unroll
            for (int c = 0; c < 16; ++c) {
                float xm = (xred[c] + xred[16 + c] + xred[32 + c] + xred[48 + c]) * (1.f / 256.f);
                a += xm * ((t < 32) ? loadf(wq, c * 32 + d, isf32)
                                    : loadf(wk, c * 32 + d, isf32));
            }
            if (t < 32) qv0[bn * 32 + d] = a; else kv0[bn * 32 + d] = a;
        }
    }
}

// ---------------- fused iteration: one block per (b, patch) ----------------
// EXACT R9 structure (measured best: ~38 us/dispatch). Double-buffered globals:
// reads ONLY Xin/qin/kin, writes ONLY Xout/qout/kout (last iter -> d_out NCHW).
// No min-waves launch bound, 1-ahead neighbor prefetch, single static sAH.
__global__ __launch_bounds__(256) void iter_kernel(
    const short* __restrict__ Xin, short* __restrict__ Xout,
    const float* __restrict__ qin, const float* __restrict__ kin,
    float* __restrict__ qout, float* __restrict__ kout,
    const float* __restrict__ Tswz,
    const short* __restrict__ WmS,
    const short* __restrict__ WgS,
    const short* __restrict__ WcS,
    const float* __restrict__ Wf,
    const int* __restrict__ counts, const int* __restrict__ nbrs,
    const int* __restrict__ flagp, void* __restrict__ out, int last)
{
    __shared__ __align__(16) short sAH[324 * SAH_STRIDE];  // ch0-15=nbrX/Magg, ch16-31=h/rh
    __shared__ float evs[4];
    __shared__ float xred[64];
    int bn = blockIdx.x, b = bn >> 6, i = bn & 63;
    int t = threadIdx.x, lane = t & 63, wv = t >> 6;
    int quad = lane >> 4, n16 = lane & 15;

    // ---- neighbor table (one int4) + neighbor-0 prefetch ----
    int4 nb4 = *(const int4*)(nbrs + i * 4);
    int deg = counts[i];
    int ejl[4] = {nb4.x, nb4.y, nb4.z, nb4.w};
    bf16x8 nbA0, nbA1, nbB0, nbB1;
    if (deg > 0) {
        const short* mp = Xin + (b * 64 + ejl[0]) * 4096 + t * 16;
        nbA0 = *(const bf16x8*)(mp);
        nbA1 = *(const bf16x8*)(mp + 8);
    }

    // per-lane constants
    float T_lane[16];
#pragma unroll
    for (int r = 0; r < 16; ++r) T_lane[r] = Tswz[t * 16 + r];
    float gb_l = Wf[11793 + n16];
    float bm_l = Wf[3392 + n16];

    const short* xown = Xin + bn * 4096;

    // ---- phase A: stage own h into ch16-31; zero borders (all 32 ch) ----
    for (int p = t; p < 324; p += 256) {
        int yy = p / 18 - 1, xx = p % 18 - 1;
        short* row = sAH + p * SAH_STRIDE;
        if ((unsigned)yy < 16u && (unsigned)xx < 16u) {
            const short* src = xown + (yy * 16 + xx) * 16;
            *(bf16x8*)(row + 16) = *(const bf16x8*)(src);
            *(bf16x8*)(row + 24) = *(const bf16x8*)(src + 8);
        } else {
            bf16x8 z = {0, 0, 0, 0, 0, 0, 0, 0};
            *(bf16x8*)(row) = z;      *(bf16x8*)(row + 8) = z;
            *(bf16x8*)(row + 16) = z; *(bf16x8*)(row + 24) = z;
        }
    }

    // ---- phase B: edge MLP, one wave per incoming edge (4 accumulators) ----
    if (wv < deg) {
        int ej = ejl[wv];
        float h0 = (lane < 32) ? qin[bn * 32 + lane]
                               : kin[(b * 64 + ej) * 32 + (lane - 32)];
        const float* W1 = Wf + 3408;
        const float* W2 = Wf + 7568;
        float p0 = 0.f, p1 = 0.f, p2 = 0.f, p3 = 0.f;
#pragma unroll
        for (int j = 0; j < 64; j += 4) {
            p0 += __shfl(h0, j + 0, 64) * W1[(j + 0) * 64 + lane];
            p1 += __shfl(h0, j + 1, 64) * W1[(j + 1) * 64 + lane];
            p2 += __shfl(h0, j + 2, 64) * W1[(j + 2) * 64 + lane];
            p3 += __shfl(h0, j + 3, 64) * W1[(j + 3) * 64 + lane];
        }
        float a1 = fmaxf(Wf[7504 + lane] + ((p0 + p1) + (p2 + p3)), 0.f);
        p0 = p1 = p2 = p3 = 0.f;
#pragma unroll
        for (int j = 0; j < 64; j += 4) {
            p0 += __shfl(a1, j + 0, 64) * W2[(j + 0) * 64 + lane];
            p1 += __shfl(a1, j + 1, 64) * W2[(j + 1) * 64 + lane];
            p2 += __shfl(a1, j + 2, 64) * W2[(j + 2) * 64 + lane];
            p3 += __shfl(a1, j + 3, 64) * W2[(j + 3) * 64 + lane];
        }
        float a2 = fmaxf(Wf[11664 + lane] + ((p0 + p1) + (p2 + p3)), 0.f);
        float pe = a2 * Wf[11728 + lane];
#pragma unroll
        for (int off = 32; off; off >>= 1) pe += __shfl_down(pe, off, 64);
        if (lane == 0) evs[wv] = pe + Wf[11792];
    }
    __syncthreads();   // h staged + evs ready

    // ---- phase C: per-neighbor M conv from LDS-staged padded tile ----
    f32x4 magg[4];
#pragma unroll
    for (int mt = 0; mt < 4; ++mt) magg[mt] = (f32x4){0.f, 0.f, 0.f, 0.f};
    int pp = ((t >> 4) + 1) * 18 + (t & 15) + 1;   // own pixel, padded coords
    for (int ii = 0; ii < deg; ++ii) {
        // stage current neighbor (regs -> LDS ch0-15); prefetch next (1-ahead only)
        *(bf16x8*)(sAH + pp * SAH_STRIDE) = nbA0;
        *(bf16x8*)(sAH + pp * SAH_STRIDE + 8) = nbA1;
        if (ii + 1 < deg) {
            const short* mp = Xin + (b * 64 + ejl[ii + 1]) * 4096 + t * 16;
            nbB0 = *(const bf16x8*)(mp);
            nbB1 = *(const bf16x8*)(mp + 8);
        }
        __syncthreads();
        float evv = evs[ii];
        f32x4 acc[4];
#pragma unroll
        for (int mt = 0; mt < 4; ++mt) acc[mt] = (f32x4){bm_l, bm_l, bm_l, bm_l};
#pragma unroll
        for (int sp = 0; sp < 5; ++sp) {
            bf16x8 Bf = *(const bf16x8*)(WmS + sp * 512 + lane * 8);
            int s2 = sp * 2 + (quad >> 1);
            if (s2 > 8) s2 = 8;                  // phantom shift: B half is zero
            int ky = s2 / 3, kx = s2 - (s2 / 3) * 3;
            int cib = (quad & 1) * 8;
#pragma unroll
            for (int mt = 0; mt < 4; ++mt) {
                int pc = (wv * 4 + mt + ky) * 18 + n16 + kx;
                bf16x8 A = *(const bf16x8*)(sAH + pc * SAH_STRIDE + cib);
                acc[mt] = __builtin_amdgcn_mfma_f32_16x16x32_bf16(A, Bf, acc[mt], 0, 0, 0);
            }
        }
#pragma unroll
        for (int mt = 0; mt < 4; ++mt)
#pragma unroll
            for (int r = 0; r < 4; ++r)
                magg[mt][r] += sigm(evv * T_lane[mt * 4 + r] + gb_l) * acc[mt][r];
        nbA0 = nbB0; nbA1 = nbB1;
        __syncthreads();   // conv reads done before next stage overwrites
    }
    // ---- phase D: M_agg -> ch0-15 interior (C-layout: every slot exactly once) ----
#pragma unroll
    for (int mt = 0; mt < 4; ++mt)
#pragma unroll
        for (int r = 0; r < 4; ++r) {
            int p = (wv * 4 + mt + 1) * 18 + quad * 4 + r + 1;
            sAH[p * SAH_STRIDE + n16] = f2bs(magg[mt][r]);
        }
    __syncthreads();

    // ---- zr conv: 9 shifts x 2 ntiles x 4 Mtiles ----
    float bz = Wf[21025 + n16], br = Wf[21025 + 16 + n16];
    f32x4 accZ[4], accR[4];
#pragma unroll
    for (int mt = 0; mt < 4; ++mt) {
        accZ[mt] = (f32x4){bz, bz, bz, bz};
        accR[mt] = (f32x4){br, br, br, br};
    }
#pragma unroll
    for (int s = 0; s < 9; ++s) {
        int ky = s / 3, kx = s - (s / 3) * 3;
        bf16x8 B0 = *(const bf16x8*)(WgS + (s * 2 + 0) * 512 + lane * 8);
        bf16x8 B1 = *(const bf16x8*)(WgS + (s * 2 + 1) * 512 + lane * 8);
#pragma unroll
        for (int mt = 0; mt < 4; ++mt) {
            int pc = (wv * 4 + mt + ky) * 18 + n16 + kx;
            bf16x8 A = *(const bf16x8*)(sAH + pc * SAH_STRIDE + quad * 8);
            accZ[mt] = __builtin_amdgcn_mfma_f32_16x16x32_bf16(A, B0, accZ[mt], 0, 0, 0);
            accR[mt] = __builtin_amdgcn_mfma_f32_16x16x32_bf16(A, B1, accR[mt], 0, 0, 0);
        }
    }
    // ---- z, r, h, r*h ----
    float zf[16], hf[16], rh[16];
#pragma unroll
    for (int mt = 0; mt < 4; ++mt)
#pragma unroll
        for (int r = 0; r < 4; ++r) {
            int k = mt * 4 + r;
            int ps = (wv * 4 + mt + 1) * 18 + quad * 4 + r + 1;
            hf[k] = bs2f(sAH[ps * SAH_STRIDE + 16 + n16]);
            zf[k] = sigm(accZ[mt][r]);
            rh[k] = sigm(accR[mt][r]) * hf[k];
        }
    __syncthreads();
#pragma unroll
    for (int mt = 0; mt < 4; ++mt)
#pragma unroll
        for (int r = 0; r < 4; ++r) {
            int ps = (wv * 4 + mt + 1) * 18 + quad * 4 + r + 1;
            sAH[ps * SAH_STRIDE + 16 + n16] = f2bs(rh[mt * 4 + r]);
        }
    __syncthreads();

    // ---- cand conv ----
    float bcl = Wf[25665 + n16];
    f32x4 accC[4];
#pragma unroll
    for (int mt = 0; mt < 4; ++mt) accC[mt] = (f32x4){bcl, bcl, bcl, bcl};
#pragma unroll
    for (int s = 0; s < 9; ++s) {
        int ky = s / 3, kx = s - (s / 3) * 3;
        bf16x8 Bc = *(const bf16x8*)(WcS + s * 512 + lane * 8);
#pragma unroll
        for (int mt = 0; mt < 4; ++mt) {
            int pc = (wv * 4 + mt + ky) * 18 + n16 + kx;
            bf16x8 A = *(const bf16x8*)(sAH + pc * SAH_STRIDE + quad * 8);
            accC[mt] = __builtin_amdgcn_mfma_f32_16x16x32_bf16(A, Bc, accC[mt], 0, 0, 0);
        }
    }
    // ---- epilogue: nx = (1-z)h + z*tanh(cand) ----
    float nxv[16];
#pragma unroll
    for (int mt = 0; mt < 4; ++mt)
#pragma unroll
        for (int r = 0; r < 4; ++r) {
            int k = mt * 4 + r;
            nxv[k] = (1.f - zf[k]) * hf[k] + zf[k] * tanh_fast(accC[mt][r]);
        }

    if (!last) {
        // write Xout [pix][ch]; q/k of new X for next iteration
        short* xo = Xout + bn * 4096;
        float ssum = 0.f;
#pragma unroll
        for (int mt = 0; mt < 4; ++mt)
#pragma unroll
            for (int r = 0; r < 4; ++r) {
                int k = mt * 4 + r;
                ssum += nxv[k];
                int pix = (wv * 4 + mt) * 16 + quad * 4 + r;
                xo[pix * 16 + n16] = f2bs(nxv[k]);
            }
        ssum += __shfl_xor(ssum, 16, 64);
        ssum += __shfl_xor(ssum, 32, 64);
        if (lane < 16) xred[wv * 16 + lane] = ssum;
        __syncthreads();
        if (t < 64) {
            int d = t & 31;
            const float* W = (t < 32) ? Wf : Wf + 544;
            float a = (t < 32) ? Wf[512 + d] : Wf[1056 + d];
#pragma unroll
            for (int c = 0; c < 16; ++c) {
                float xc = (xred[c] + xred[16 + c] + xred[32 + c] + xred[48 + c]) * (1.f / 256.f);
                a += xc * W[c * 32 + d];
            }
            if (t < 32) qout[bn * 32 + d] = a; else kout[bn * 32 + d] = a;
        }
    } else {
        // final iteration: write d_out directly in (B,C,128,128)
        int isf32 = *flagp;
        int pq = i >> 3, qq = i & 7;
#pragma unroll
        for (int mt = 0; mt < 4; ++mt) {
            long base = ((long)(b * 16 + n16) * 128 + pq * 16 + wv * 4 + mt) * 128
                        + qq * 16 + quad * 4;
            if (isf32) {
                f32x4 v = {nxv[mt * 4], nxv[mt * 4 + 1], nxv[mt * 4 + 2], nxv[mt * 4 + 3]};
                *(f32x4*)((float*)out + base) = v;
            } else {
                s16x4 v = {f2bs(nxv[mt * 4]), f2bs(nxv[mt * 4 + 1]),
                           f2bs(nxv[mt * 4 + 2]), f2bs(nxv[mt * 4 + 3])};
                *(s16x4*)((short*)out + base) = v;
            }
        }
    }
}

extern "C" void kernel_launch(void* const* d_in, const int* in_sizes, int n_in,
                              void* d_out, int out_size, void* d_ws, size_t ws_size,
                              hipStream_t stream)
{
    const void* seed = d_in[0];
    const int* edge = (const int*)d_in[1];
    int E = in_sizes[1] / 2;  // 224

    float* ws = (float*)d_ws;
    short* Xb0 = (short*)ws;                         // 8 MB
    short* Xb1 = (short*)(ws + 2097152);             // 8 MB
    float* qv0 = ws + 4194304;                       // 32768 each
    float* kv0 = qv0 + 32768;
    float* qv1 = kv0 + 32768;
    float* kv1 = qv1 + 32768;
    float* Tswz = kv1 + 32768;                       // 4096
    float* Wf = Tswz + 4096;                         // 25681
    int* nbrs = (int*)(ws + 4355168);                // 256 ints, 16B-aligned
    int* counts = nbrs + 256;                        // 64
    int* flag = counts + 64;                         // 1
    __hip_bfloat16* swz = (__hip_bfloat16*)(ws + 4355600);  // 16384 bf16, 16B-aligned

    const short* WgS = (const short*)swz;
    const short* WcS = (const short*)(swz + 9216);
    const short* WmS = (const short*)(swz + 13824);

    setup_kernel<<<Bt * Nt, 256, 0, stream>>>(
        seed,
        d_in[2], d_in[3], d_in[4], d_in[5], d_in[6], d_in[7], d_in[8], d_in[9],
        d_in[10], d_in[11], d_in[12], d_in[13], d_in[14], d_in[15], d_in[16],
        d_in[17], d_in[18], d_in[19],
        edge, E, Wf, Tswz, counts, nbrs, swz, Xb0, qv0, kv0, flag);

    short* Xs[2] = {Xb0, Xb1};
    float* qs[2] = {qv0, qv1};
    float* ks[2] = {kv0, kv1};
    for (int it = 0; it < KITERt; ++it) {
        int in = it & 1, on = in ^ 1;
        int last = (it == KITERt - 1);
        iter_kernel<<<Bt * Nt, 256, 0, stream>>>(
            Xs[in], Xs[on], qs[in], ks[in], qs[on], ks[on],
            Tswz, WmS, WgS, WcS, Wf, counts, nbrs, flag, d_out, last);
    }
}